// Round 2
// baseline (2680.196 us; speedup 1.0000x reference)
//
#include <hip/hip_runtime.h>
#include <math.h>

// DGM Black-Scholes PDE residual via forward-mode jets.
//
// Channels c: 0 = value; 1 = d/dt; 2..6 = d/dx1..dx5; 7..11 = d2/dx1^2..dx5^2.
// All derivative directions are independent input coords, so pure second
// derivatives suffice for the Laplacian; linear layers propagate all 12
// channels through the same weight matrix; tanh / product / gate-combine
// have closed-form jet rules.
//
// One wave (64 lanes) per sample; lane l owns hidden units j0=2l, j0+1.
// A (LDS, [128][16] floats) holds the hidden-state jet rows for one sample;
// the 6 constant header rows (tx jet: one-hot derivs, zero 2nd derivs) are
// folded into the matmul from registers instead of stored.

namespace {
constexpr int HID_  = 128;
constexpr int NCH   = 12;
constexpr int ASTR  = 16;    // row stride in floats (12 used, 64B row, f4-aligned)
constexpr int SPB   = 4;     // samples (waves) per block
constexpr float MU_   = 0.05f;
constexpr float HSIG2 = 0.5f * 0.2f * 0.2f;  // 0.02
}

__global__ __launch_bounds__(64 * SPB, 3)
void dgm_pde(const float* __restrict__ t,
             const float* __restrict__ x,
             const float* __restrict__ Win,    // [6][128]
             const float* __restrict__ b_in,   // [128]
             const float* __restrict__ Wg,     // [3][4][134][128]
             const float* __restrict__ bg,     // [3][4][128]
             const float* __restrict__ Wout,   // [128]
             const float* __restrict__ bout,   // [1]
             float* __restrict__ out)          // [B]
{
    __shared__ __align__(16) float Abuf[SPB][HID_][ASTR];
    const int wv = threadIdx.x >> 6;
    const int l  = threadIdx.x & 63;
    const int samp = blockIdx.x * SPB + wv;
    float (*A)[ASTR] = Abuf[wv];
    const int j0 = 2 * l;

    // ---- tx (broadcast scalar loads, L1-served) ----
    float tx[6];
    tx[0] = t[samp];
    #pragma unroll
    for (int m = 1; m < 6; ++m) tx[m] = x[samp * 5 + m - 1];

    // ---- input layer: S = tanh(tx @ Win + b_in), jet-propagated ----
    float S0[NCH], S1[NCH];
    {
        float w0[6], w1[6];
        #pragma unroll
        for (int m = 0; m < 6; ++m) {
            const float2 ww = *reinterpret_cast<const float2*>(Win + m * HID_ + j0);
            w0[m] = ww.x; w1[m] = ww.y;
        }
        const float2 bb = *reinterpret_cast<const float2*>(b_in + j0);
        float p0 = bb.x, p1 = bb.y;
        #pragma unroll
        for (int m = 0; m < 6; ++m) { p0 = fmaf(tx[m], w0[m], p0); p1 = fmaf(tx[m], w1[m], p1); }
        const float v0 = tanhf(p0), v1 = tanhf(p1);
        const float t20 = 1.f - v0 * v0, t21 = 1.f - v1 * v1;
        S0[0] = v0; S1[0] = v1;
        #pragma unroll
        for (int m = 0; m < 6; ++m) { S0[1 + m] = t20 * w0[m]; S1[1 + m] = t21 * w1[m]; }
        #pragma unroll
        for (int k = 1; k <= 5; ++k) {
            S0[6 + k] = -2.f * v0 * t20 * w0[k] * w0[k];
            S1[6 + k] = -2.f * v1 * t21 * w1[k] * w1[k];
        }
    }

    // ---- helpers ----
    auto storeA = [&](const float* a0, const float* a1) {
        #pragma unroll
        for (int c = 0; c < NCH; c += 4) {
            *reinterpret_cast<float4*>(&A[j0][c])     = make_float4(a0[c], a0[c+1], a0[c+2], a0[c+3]);
            *reinterpret_cast<float4*>(&A[j0 + 1][c]) = make_float4(a1[c], a1[c+1], a1[c+2], a1[c+3]);
        }
    };
    // Full gate matmul over K = 6 (register header) + 128 (LDS jet rows).
    auto matmul = [&](const float* __restrict__ Wgt, const float* __restrict__ bgt,
                      float* acc0, float* acc1) {
        #pragma unroll
        for (int c = 0; c < NCH; ++c) { acc0[c] = 0.f; acc1[c] = 0.f; }
        const float2 bb = *reinterpret_cast<const float2*>(bgt + j0);
        acc0[0] = bb.x; acc1[0] = bb.y;
        // header rows: value ch gets tx[m]*w, deriv ch (1+m) gets w, 2nd derivs 0
        #pragma unroll
        for (int m = 0; m < 6; ++m) {
            const float2 w = *reinterpret_cast<const float2*>(Wgt + m * HID_ + j0);
            acc0[0] = fmaf(tx[m], w.x, acc0[0]);
            acc1[0] = fmaf(tx[m], w.y, acc1[0]);
            acc0[1 + m] += w.x;
            acc1[1 + m] += w.y;
        }
        // body rows: general 12-channel jet propagation
        #pragma unroll 2
        for (int h = 0; h < HID_; ++h) {
            const float2 w = *reinterpret_cast<const float2*>(Wgt + (6 + h) * HID_ + j0);
            const float4* A4 = reinterpret_cast<const float4*>(A[h]);
            const float4 a0 = A4[0], a1 = A4[1], a2 = A4[2];
            const float av[12] = {a0.x, a0.y, a0.z, a0.w,
                                  a1.x, a1.y, a1.z, a1.w,
                                  a2.x, a2.y, a2.z, a2.w};
            #pragma unroll
            for (int c = 0; c < NCH; ++c) {
                acc0[c] = fmaf(av[c], w.x, acc0[c]);
                acc1[c] = fmaf(av[c], w.y, acc1[c]);
            }
        }
    };
    auto act = [&](float* a) {  // in-place tanh jet: 2nd derivs first (read 1st derivs + value)
        const float v  = tanhf(a[0]);
        const float t2 = 1.f - v * v;
        #pragma unroll
        for (int k = 1; k <= 5; ++k) a[6 + k] = t2 * a[6 + k] - 2.f * v * t2 * a[1 + k] * a[1 + k];
        #pragma unroll
        for (int m = 0; m < 6; ++m) a[1 + m] = t2 * a[1 + m];
        a[0] = v;
    };

    storeA(S0, S1);
    __syncthreads();

    // ---- 3 DGM layers ----
    float Z0[NCH], Z1[NCH], G0[NCH], G1[NCH], R0[NCH], R1[NCH];
    constexpr int GSTride = 134 * HID_;
    #pragma unroll 1
    for (int layer = 0; layer < 3; ++layer) {
        const float* WL = Wg + (size_t)layer * 4 * GSTride;
        const float* bL = bg + layer * 4 * HID_;

        matmul(WL + 0 * GSTride, bL + 0 * HID_, Z0, Z1); act(Z0); act(Z1);
        matmul(WL + 1 * GSTride, bL + 1 * HID_, G0, G1); act(G0); act(G1);
        matmul(WL + 2 * GSTride, bL + 2 * HID_, R0, R1); act(R0); act(R1);

        // P = S ⊙ R (jet product), in place into R: dd first, then d, then value
        #pragma unroll
        for (int k = 1; k <= 5; ++k) {
            R0[6+k] = S0[6+k]*R0[0] + 2.f*S0[1+k]*R0[1+k] + S0[0]*R0[6+k];
            R1[6+k] = S1[6+k]*R1[0] + 2.f*S1[1+k]*R1[1+k] + S1[0]*R1[6+k];
        }
        #pragma unroll
        for (int m = 0; m < 6; ++m) {
            R0[1+m] = S0[1+m]*R0[0] + S0[0]*R0[1+m];
            R1[1+m] = S1[1+m]*R1[0] + S1[0]*R1[1+m];
        }
        R0[0] = S0[0]*R0[0];
        R1[0] = S1[0]*R1[0];

        __syncthreads();          // everyone done reading A (S jets)
        storeA(R0, R1);           // A rows now hold S*R jets
        __syncthreads();

        matmul(WL + 3 * GSTride, bL + 3 * HID_, R0, R1); act(R0); act(R1);  // H in R

        // Snew = (1-G)⊙H + Z⊙S, in place into S: dd, d, value order
        // (dd reads old d/value; d reads old value; value last)
        #pragma unroll
        for (int k = 1; k <= 5; ++k) {
            S0[6+k] = (1.f - G0[0])*R0[6+k] - G0[6+k]*R0[0] - 2.f*G0[1+k]*R0[1+k]
                    + Z0[6+k]*S0[0] + 2.f*Z0[1+k]*S0[1+k] + Z0[0]*S0[6+k];
            S1[6+k] = (1.f - G1[0])*R1[6+k] - G1[6+k]*R1[0] - 2.f*G1[1+k]*R1[1+k]
                    + Z1[6+k]*S1[0] + 2.f*Z1[1+k]*S1[1+k] + Z1[0]*S1[6+k];
        }
        #pragma unroll
        for (int m = 0; m < 6; ++m) {
            S0[1+m] = (1.f - G0[0])*R0[1+m] - G0[1+m]*R0[0] + Z0[1+m]*S0[0] + Z0[0]*S0[1+m];
            S1[1+m] = (1.f - G1[0])*R1[1+m] - G1[1+m]*R1[0] + Z1[1+m]*S1[0] + Z1[0]*S1[1+m];
        }
        S0[0] = (1.f - G0[0])*R0[0] + Z0[0]*S0[0];
        S1[0] = (1.f - G1[0])*R1[0] + Z1[0]*S1[0];

        __syncthreads();          // everyone done reading A (S*R jets)
        storeA(S0, S1);
        __syncthreads();
    }

    // ---- PDE residual epilogue ----
    // pde = grad_t + MU * sum_k x_k * du/dx_k + 0.5*sig^2 * lap - MU * u
    float comb0 = S0[1] - MU_ * S0[0];
    float comb1 = S1[1] - MU_ * S1[0];
    #pragma unroll
    for (int k = 1; k <= 5; ++k) {
        comb0 += MU_ * tx[k] * S0[1 + k] + HSIG2 * S0[6 + k];
        comb1 += MU_ * tx[k] * S1[1 + k] + HSIG2 * S1[6 + k];
    }
    const float2 wo = *reinterpret_cast<const float2*>(Wout + j0);
    float part = comb0 * wo.x + comb1 * wo.y;
    #pragma unroll
    for (int off = 32; off > 0; off >>= 1) part += __shfl_xor(part, off, 64);
    if (l == 0) out[samp] = part - MU_ * bout[0];
}

extern "C" void kernel_launch(void* const* d_in, const int* in_sizes, int n_in,
                              void* d_out, int out_size, void* d_ws, size_t ws_size,
                              hipStream_t stream)
{
    const float* t    = (const float*)d_in[0];
    const float* x    = (const float*)d_in[1];
    const float* Win  = (const float*)d_in[2];
    const float* b_in = (const float*)d_in[3];
    const float* Wg   = (const float*)d_in[4];
    const float* bg   = (const float*)d_in[5];
    const float* Wout = (const float*)d_in[6];
    const float* bout = (const float*)d_in[7];
    float* out = (float*)d_out;

    const int nB = in_sizes[0];           // 32768, divisible by SPB
    dgm_pde<<<nB / SPB, 64 * SPB, 0, stream>>>(t, x, Win, b_in, Wg, bg, Wout, bout, out);
}